// Round 12
// baseline (251.668 us; speedup 1.0000x reference)
//
#include <hip/hip_runtime.h>
#include <stdint.h>

#define BB 8192
#define DD 128
#define MARGIN 1.0f
#define CCAP 48
#define NCH 8              // col-chunks; 512 blocks = 64 panels x 8 chunks
#define CHCOLS (BB / NCH)  // 1024 cols per chunk
#define TPC (CHCOLS / 64)  // 16 B-tiles of 64 cols
#define NBLK 512           // exactly 2 blocks/CU x 256 CU co-resident
#define RPB 16             // rows per block in prep/pos phases

typedef __attribute__((ext_vector_type(8))) short short8_t;
typedef __attribute__((ext_vector_type(4))) float f32x4;

// async global->LDS, 16B per lane; LDS dest is wave-uniform base + lane*16
#define GLL16(g, l)                                                                   \
  __builtin_amdgcn_global_load_lds(                                                   \
      (const __attribute__((address_space(1))) unsigned int*)(g),                     \
      (__attribute__((address_space(3))) unsigned int*)(l), 16, 0, 0)

__device__ __forceinline__ unsigned short f2bf(float f) {
  unsigned u = __float_as_uint(f);
  u = (u + 0x7fffu + ((u >> 16) & 1u)) >> 16;  // RNE
  return (unsigned short)u;
}

// grid barrier: device-scope atomics (coherence point), tid0-only poll with
// s_sleep backoff; __threadfence release/acquire makes plain stores visible
// across XCD L2s (tid0's cache-wide wb/inv covers the whole block's stores
// since __syncthreads already drained them to L2).
__device__ __forceinline__ void gridbar(unsigned* c) {
  __syncthreads();
  if (threadIdx.x == 0) {
    __threadfence();
    atomicAdd(c, 1u);
    while (atomicAdd(c, 0u) < NBLK) __builtin_amdgcn_s_sleep(32);
    __threadfence();
  }
  __syncthreads();
}

// ---------------- ONE persistent kernel: prep -> dist_min -> pos_loss -> finalize ----
__global__ __launch_bounds__(256, 2) void fused_kernel(
    const float* __restrict__ E, const int* __restrict__ lab,
    unsigned short* __restrict__ Ebf, float* __restrict__ sq,
    int* __restrict__ cls_cnt, int* __restrict__ cls_idx,
    float* __restrict__ part, float* __restrict__ ptot, int* __restrict__ pcnt,
    unsigned* __restrict__ ctr, float* __restrict__ out) {
  __shared__ __align__(16) char ldsA[128 * 256];    // 32 KB, swizzled
  __shared__ __align__(16) char ldsB[2][64 * 256];  // 2 x 16 KB, swizzled
  __shared__ int labC[CHCOLS];                      // 4 KB
  __shared__ float hC[CHCOLS];                      // 4 KB
  __shared__ int labI[128];
  __shared__ float redMin[4][64];                   // also reused as reduce scratch

  const int tid = threadIdx.x;
  const int b = blockIdx.x;
  const int wid = tid >> 6, lane = tid & 63;
  const int l4 = lane >> 4, c16 = lane & 15;

  // ================= phase 0: prep (16 rows/block) =================
#pragma unroll
  for (int rr = 0; rr < 4; rr++) {
    int row = b * RPB + wid * 4 + rr;
    const float2 v = *(const float2*)(E + (size_t)row * DD + lane * 2);
    ushort2 bb;
    bb.x = f2bf(v.x);
    bb.y = f2bf(v.y);
    *(ushort2*)(Ebf + (size_t)row * DD + lane * 2) = bb;
    float s = v.x * v.x + v.y * v.y;
    for (int off = 1; off < 64; off <<= 1) s += __shfl_xor(s, off);
    if (lane == 0) {
      sq[row] = s;
      int labi = lab[row];
      int pp = atomicAdd(&cls_cnt[labi], 1);
      if (pp < CCAP) cls_idx[labi * CCAP + pp] = row;
    }
  }
  gridbar(&ctr[0]);  // Ebf, sq, buckets globally visible

  // ================= phase 1: masked-min distance GEMM =================
  {
    const int p = b >> 3, c = b & (NCH - 1);
    const int rI = p * 128;
    const int cBase = c * CHCOLS;
    const int wr = wid >> 1, wc = wid & 1;
    const int rowbase = wr * 64;
    const int cl = c16, rg = l4;

#define STAGE_A()                                                                   \
  {                                                                                 \
    _Pragma("unroll") for (int q = 0; q < 8; q++) {                                 \
      int r = wid * 32 + q * 4 + l4;                                                \
      int chunk = c16 ^ (r & 7);                                                    \
      GLL16((const char*)Ebf + (size_t)(rI + r) * 256 + chunk * 16,                 \
            ldsA + wid * 8192 + q * 1024);                                          \
    }                                                                               \
  }
#define STAGE_B(tt, buf)                                                            \
  {                                                                                 \
    _Pragma("unroll") for (int q = 0; q < 4; q++) {                                 \
      int r = wid * 16 + q * 4 + l4;                                                \
      int chunk = c16 ^ (r & 7);                                                    \
      GLL16((const char*)Ebf + (size_t)(cBase + (tt)*64 + r) * 256 + chunk * 16,    \
            (buf) + wid * 4096 + q * 1024);                                         \
    }                                                                               \
  }

    STAGE_A();
    STAGE_B(0, ldsB[0]);
    STAGE_B(1, ldsB[1]);

    for (int q = tid; q < CHCOLS; q += 256) {
      labC[q] = lab[cBase + q];
      hC[q] = 0.5f * sq[cBase + q];
    }
    if (tid < 128) labI[tid] = lab[rI + tid];

    int il[4][4];
    float tm[4][4];
#pragma unroll
    for (int m = 0; m < 4; m++)
#pragma unroll
      for (int r = 0; r < 4; r++) tm[m][r] = __builtin_huge_valf();

#pragma unroll 2
    for (int t = 0; t < TPC; t++) {
      // release stage(t) [+A & phase-0 residue at t=0], keep stage(t+1) in flight
      if (t < TPC - 1)
        asm volatile("s_waitcnt vmcnt(4) lgkmcnt(0)" ::: "memory");
      else
        asm volatile("s_waitcnt vmcnt(0) lgkmcnt(0)" ::: "memory");
      __builtin_amdgcn_sched_barrier(0);
      __builtin_amdgcn_s_barrier();
      __builtin_amdgcn_sched_barrier(0);

      if (t == 0) {
#pragma unroll
        for (int m = 0; m < 4; m++)
#pragma unroll
          for (int r = 0; r < 4; r++) il[m][r] = labI[rowbase + m * 16 + rg * 4 + r];
      }

      int jl[2];
      float jh[2];
#pragma unroll
      for (int n = 0; n < 2; n++) {
        int j = t * 64 + wc * 32 + n * 16 + cl;
        jl[n] = labC[j];
        jh[n] = hC[j];
      }

      f32x4 acc[4][2];
#pragma unroll
      for (int m = 0; m < 4; m++)
#pragma unroll
        for (int n = 0; n < 2; n++) acc[m][n] = (f32x4){0.f, 0.f, 0.f, 0.f};

#pragma unroll
      for (int kk = 0; kk < 4; kk++) {
        const int kb = kk * 64 + rg * 16;
        short8_t a[4], bfr[2];
#pragma unroll
        for (int m = 0; m < 4; m++) {
          int row = rowbase + m * 16 + cl;
          a[m] = *(const short8_t*)(ldsA + row * 256 + (kb ^ ((row & 7) << 4)));
        }
#pragma unroll
        for (int n = 0; n < 2; n++) {
          int row = wc * 32 + n * 16 + cl;
          bfr[n] = *(const short8_t*)(ldsB[t & 1] + row * 256 + (kb ^ ((row & 7) << 4)));
        }
#pragma unroll
        for (int m = 0; m < 4; m++)
#pragma unroll
          for (int n = 0; n < 2; n++)
            acc[m][n] = __builtin_amdgcn_mfma_f32_16x16x32_bf16(a[m], bfr[n], acc[m][n], 0, 0, 0);
      }

#pragma unroll
      for (int m = 0; m < 4; m++)
#pragma unroll
        for (int n = 0; n < 2; n++) {
          f32x4 v = acc[m][n];
#pragma unroll
          for (int r = 0; r < 4; r++) {
            float u = jh[n] - v[r];
            if (il[m][r] != jl[n]) tm[m][r] = fminf(tm[m][r], u);
          }
        }

      __builtin_amdgcn_s_barrier();
      __builtin_amdgcn_sched_barrier(0);
      if (t + 2 < TPC) STAGE_B(t + 2, ldsB[t & 1]);
    }

    // cross-lane + cross-wave min, plain stores to part[c][row]
#pragma unroll
    for (int m = 0; m < 4; m++)
#pragma unroll
      for (int r = 0; r < 4; r++) {
        float t = tm[m][r];
        t = fminf(t, __shfl_xor(t, 1));
        t = fminf(t, __shfl_xor(t, 2));
        t = fminf(t, __shfl_xor(t, 4));
        t = fminf(t, __shfl_xor(t, 8));
        tm[m][r] = t;
      }
    if (cl == 0) {
#pragma unroll
      for (int m = 0; m < 4; m++)
#pragma unroll
        for (int r = 0; r < 4; r++) redMin[wid][m * 16 + rg * 4 + r] = tm[m][r];
    }
    __syncthreads();
    if (wc == 0) {
      float v = fminf(redMin[wid][lane], redMin[wid + 1][lane]);
      part[(size_t)c * BB + rI + rowbase + lane] = v;
    }
  }
  gridbar(&ctr[1]);  // part[] globally visible

  // ================= phase 2: positives + hardest-neg, exact fp32 =================
  {
    float tsum = 0.0f;
    int tcnt = 0;
#pragma unroll
    for (int aa = 0; aa < 4; aa++) {
      const int i = b * RPB + wid * 4 + aa;
      const int labi = lab[i];
      int n = cls_cnt[labi];
      if (n > CCAP) n = CCAP;
      const float2 ei = *(const float2*)(E + (size_t)i * DD + lane * 2);
      const float sqi = sq[i];
      float mn = __builtin_huge_valf();
#pragma unroll
      for (int cc = 0; cc < NCH; cc++) mn = fminf(mn, part[(size_t)cc * BB + i]);
      const float hn = fmaxf(sqi + 2.0f * mn, 0.0f);  // relu(min raw d)
      for (int s = 0; s < n; s++) {
        int j = cls_idx[labi * CCAP + s];
        if (j == i) continue;
        float2 ej = *(const float2*)(E + (size_t)j * DD + lane * 2);
        float pp = ei.x * ej.x + ei.y * ej.y;
        for (int off = 1; off < 64; off <<= 1) pp += __shfl_xor(pp, off);
        float d = fmaxf(sqi + sq[j] - 2.0f * pp, 0.0f);
        if (hn < d) {
          tcnt++;
          tsum += d - hn + MARGIN;
        }
      }
    }
    if (lane == 0) {
      redMin[0][wid] = tsum;
      ((int*)&redMin[1][0])[wid] = tcnt;
    }
    __syncthreads();
    if (tid == 0) {
      ptot[b] = redMin[0][0] + redMin[0][1] + redMin[0][2] + redMin[0][3];
      int* sc = (int*)&redMin[1][0];
      pcnt[b] = sc[0] + sc[1] + sc[2] + sc[3];
    }
  }
  gridbar(&ctr[2]);  // ptot/pcnt globally visible

  // ================= phase 3: block 0 reduces 512 partials =================
  if (b == 0) {
    float t = 0.0f;
    int c = 0;
    for (int k = tid; k < NBLK; k += 256) {
      t += ptot[k];
      c += pcnt[k];
    }
    for (int off = 1; off < 64; off <<= 1) {
      t += __shfl_xor(t, off);
      c += __shfl_xor(c, off);
    }
    __syncthreads();  // redMin reuse
    if (lane == 0) {
      redMin[2][wid] = t;
      ((int*)&redMin[3][0])[wid] = c;
    }
    __syncthreads();
    if (tid == 0) {
      float tt = redMin[2][0] + redMin[2][1] + redMin[2][2] + redMin[2][3];
      int* sc = (int*)&redMin[3][0];
      int cc = sc[0] + sc[1] + sc[2] + sc[3];
      out[0] = tt / (float)(cc > 0 ? cc : 1);
      out[1] = (float)cc;
    }
  }
}

extern "C" void kernel_launch(void* const* d_in, const int* in_sizes, int n_in,
                              void* d_out, int out_size, void* d_ws, size_t ws_size,
                              hipStream_t stream) {
  const float* E = (const float*)d_in[0];
  const int* lab = (const int*)d_in[1];
  float* out = (float*)d_out;

  char* ws = (char*)d_ws;
  unsigned short* Ebf = (unsigned short*)ws;            // 2 MB
  float* sq = (float*)(ws + 2097152);                   // 32 KB
  int* cls_cnt = (int*)(ws + 2129920);                  // 4 KB   (zeroed)
  unsigned* ctr = (unsigned*)(ws + 2134016);            // 64 B   (zeroed)
  int* cls_idx = (int*)(ws + 2134080);                  // 192 KB
  float* part = (float*)(ws + 2330688);                 // 256 KB
  float* ptot = (float*)(ws + 2592832);                 // 2 KB
  int* pcnt = (int*)(ws + 2594880);                     // 2 KB

  hipMemsetAsync(cls_cnt, 0, 4096 + 64, stream);  // cls_cnt + barrier ctrs
  fused_kernel<<<NBLK, 256, 0, stream>>>(E, lab, Ebf, sq, cls_cnt, cls_idx,
                                         part, ptot, pcnt, ctr, out);
}